// Round 6
// baseline (847.082 us; speedup 1.0000x reference)
//
#include <hip/hip_runtime.h>
#include <hip/hip_bf16.h>
#include <hip/hip_cooperative_groups.h>

namespace cg = cooperative_groups;

// ---------------- problem constants ----------------
constexpr int kH = 1024, kS = 1024, kNH = 16, kI = 4096, kNOUT = 2560;
constexpr int kQKVN = 1536;  // Q(1024)|K(256)|V(256)
constexpr int NBLK = 512, NTHR = 256;

typedef __attribute__((ext_vector_type(8))) short short8v;
typedef __attribute__((ext_vector_type(4))) float f32x4;
typedef unsigned short u16;

#define MFMA16 __builtin_amdgcn_mfma_f32_16x16x32_bf16

__device__ __forceinline__ u16 f2bf(float f) {
  unsigned u = __float_as_uint(f);
  return (u16)((u + 0x7fffu + ((u >> 16) & 1u)) >> 16);
}
__device__ __forceinline__ float bf2f(u16 u) {
  return __uint_as_float(((unsigned)u) << 16);
}
__device__ __forceinline__ void gload16(void* lds, const void* g) {
  __builtin_amdgcn_global_load_lds(
      (const __attribute__((address_space(1))) unsigned int*)g,
      (__attribute__((address_space(3))) unsigned int*)lds, 16, 0, 0);
}

// ---------------- workspace layout (float offsets) ----------------
constexpr long OFF_H      = 0;                        // 2048x1024 f32
constexpr long OFF_HM     = OFF_H + 2097152;          // [2][1024]
constexpr long OFF_INT    = OFF_HM + 2048;            // ints: [0] flag(unused) [1..3] sel(unused) [4..9] gate [10..15] act
constexpr long OFF_GP     = OFF_INT + 64;             // [3][64][1024]
constexpr long OFF_SLAB   = OFF_GP + 196608;          // 15,204,352 bf16
constexpr long OFF_WOUTBF = OFF_SLAB + 7602176;       // 2560x1024 bf16
constexpr long OFF_HBF    = OFF_WOUTBF + 1310720;     // 2048x1024 bf16
constexpr long OFF_QKV    = OFF_HBF + 1048576;        // 2048x1536 bf16
constexpr long OFF_ATT    = OFF_QKV + 1572864;        // 2048x1024 bf16
constexpr long OFF_OBF    = OFF_ATT + 1048576;        // 2048x1024 bf16
constexpr long OFF_PBF    = OFF_OBF + 1048576;        // 2048x4096 bf16

constexpr long SB_WQ = 0, SB_WK = 1048576, SB_WV = 1310720, SB_WO = 1572864,
               SB_WG = 2621440, SB_WU = 6815744, SB_WD = 11010048, SB_TOT = 15204352;

struct MegaArgs {
  const int* ids;
  const float *emb, *semb, *Wq, *Wk, *Wv, *Wo, *Wg, *Wu, *Wd;
  const float *Wls, *bls, *Wbs, *bbs, *Wout;
  float* out;
  float* ws;
};

// ---------------- GEMM tile phase: C = A @ B.T, BM=128 BN=64 BK=64, M=2048 -------------
// MODE 0: bf16 out. 1: f32 out. 2: f32 C0 + bf16 C1. 3: dual-B, bf16 out = acc0*acc1.
// run_b: compute tiles of batch b. zf_b: (MODE2) write zero tile instead.
template <int MODE>
__device__ void gemm_phase(const u16* __restrict__ A, const u16* __restrict__ B0,
                           const u16* __restrict__ B1, void* __restrict__ C0,
                           void* __restrict__ C1, int N, int K, int ntn,
                           int run0, int run1, int zf0, int zf1,
                           u16* sA, u16* sB, u16* sB1) {
  constexpr bool USE_B1 = (MODE == 3);
  const int tid = threadIdx.x;
  const int ntiles = 16 * ntn;
  for (int t = blockIdx.x; t < ntiles; t += gridDim.x) {
    const int tm = t & 15, tn = t >> 4;
    const int m0 = tm * 128, n0 = tn * 64;
    const int run = (tm >> 3) ? run1 : run0;
    const int zf = (tm >> 3) ? zf1 : zf0;
    if (!run) {
      if (MODE == 2 && zf) {
        int r = tid >> 1, cb = n0 + (tid & 1) * 32;
        float* c0 = (float*)C0 + (long)(m0 + r) * N + cb;
        u16* c1 = (u16*)C1 + (long)(m0 + r) * N + cb;
        float4 z4 = make_float4(0.f, 0.f, 0.f, 0.f);
        ushort4 zu = {0, 0, 0, 0};
        #pragma unroll
        for (int j = 0; j < 32; j += 4) { *(float4*)(c0 + j) = z4; *(ushort4*)(c1 + j) = zu; }
      }
      continue;
    }
    const int wave = tid >> 6, lane = tid & 63;
    const int lr = lane & 15, lg = lane >> 4;
    const int wm = wave >> 1, wn = wave & 1;
    f32x4 acc[4][2] = {};
    f32x4 acc1[USE_B1 ? 4 : 1][2] = {};
    for (int k0 = 0; k0 < K; k0 += 64) {
      __syncthreads();  // previous readers done before re-staging LDS
      #pragma unroll
      for (int j = 0; j < 4; ++j) {
        int c = tid + j * 256;
        int r = c >> 3, c8 = c & 7;
        gload16((char*)sA + (wave * 64 + j * 256) * 16,
                A + (long)(m0 + r) * K + k0 + ((c8 ^ (r & 7)) * 8));
      }
      #pragma unroll
      for (int j = 0; j < 2; ++j) {
        int c = tid + j * 256;
        int r = c >> 3, c8 = c & 7;
        long gb = (long)(n0 + r) * K + k0 + ((c8 ^ (r & 7)) * 8);
        gload16((char*)sB + (wave * 64 + j * 256) * 16, B0 + gb);
        if constexpr (USE_B1)
          gload16((char*)sB1 + (wave * 64 + j * 256) * 16, B1 + gb);
      }
      __syncthreads();
      #pragma unroll
      for (int kh = 0; kh < 2; ++kh) {
        const int kb = kh * 64 + lg * 16;
        short8v av[4], bv[2], b1v[2];
        #pragma unroll
        for (int mi = 0; mi < 4; ++mi) {
          int r = wm * 64 + mi * 16 + lr;
          av[mi] = *(const short8v*)((const char*)sA + ((r * 128 + kb) ^ ((r & 7) << 4)));
        }
        #pragma unroll
        for (int ni = 0; ni < 2; ++ni) {
          int r = wn * 32 + ni * 16 + lr;
          int byte = (r * 128 + kb) ^ ((r & 7) << 4);
          bv[ni] = *(const short8v*)((const char*)sB + byte);
          if constexpr (USE_B1) b1v[ni] = *(const short8v*)((const char*)sB1 + byte);
        }
        #pragma unroll
        for (int mi = 0; mi < 4; ++mi)
          #pragma unroll
          for (int ni = 0; ni < 2; ++ni) {
            acc[mi][ni] = MFMA16(av[mi], bv[ni], acc[mi][ni], 0, 0, 0);
            if constexpr (USE_B1)
              acc1[mi][ni] = MFMA16(av[mi], b1v[ni], acc1[mi][ni], 0, 0, 0);
          }
      }
    }
    #pragma unroll
    for (int mi = 0; mi < 4; ++mi)
      #pragma unroll
      for (int ni = 0; ni < 2; ++ni)
        #pragma unroll
        for (int r = 0; r < 4; ++r) {
          long idx = (long)(m0 + wm * 64 + mi * 16 + lg * 4 + r) * N +
                     (n0 + wn * 32 + ni * 16 + lr);
          float v = acc[mi][ni][r];
          if constexpr (MODE == 0) ((u16*)C0)[idx] = f2bf(v);
          if constexpr (MODE == 1) ((float*)C0)[idx] = v;
          if constexpr (MODE == 2) { ((float*)C0)[idx] = v; ((u16*)C1)[idx] = f2bf(v); }
          if constexpr (MODE == 3) ((u16*)C0)[idx] = f2bf(v * acc1[mi][ni][r]);
        }
  }
}

// ---------------- hmean phase: wave-per-column, 2048 columns over 512 blocks ----------
__device__ void hmean_phase(const float* __restrict__ h, float* __restrict__ hm) {
  int wave = threadIdx.x >> 6, lane = threadIdx.x & 63;
  int u = blockIdx.x * 4 + wave;  // 512*4 = 2048
  int b = u >> 10, c = u & 1023;
  const float* p = h + ((long)b << 20) + c;
  float acc = 0.f;
  for (int r = lane; r < kS; r += 64) acc += p[(long)r << 10];
  #pragma unroll
  for (int off = 32; off; off >>= 1) acc += __shfl_down(acc, off, 64);
  if (lane == 0) hm[u] = acc;
}

// ---------------- rowsum(thresholded softmax) + attn = rs*V; 512 tiles ---------------
// tile: (b, kvg, qt): 16 q-rows x 4 heads of one kv-group. No max-subtract (scores tiny;
// ratio t/s is shift-invariant and margin to the 0.01 threshold is ~10x).
__device__ void rowsum_phase(const u16* __restrict__ QKV, const int* __restrict__ g_i,
                             int* __restrict__ a_i, u16* __restrict__ ATT, float* sf) {
  const int tid = threadIdx.x;
  for (int t = blockIdx.x; t < 512; t += gridDim.x) {
    int b = t >> 8, kvg = (t >> 6) & 3, qt = t & 63;
    if (!g_i[b]) continue;
    int w = tid >> 6, lane = tid & 63, lr = lane & 15, lg = lane >> 4;
    long qrow = ((long)b << 10) + qt * 16 + lr;
    short8v qlo[4], qhi[4];
    #pragma unroll
    for (int hh = 0; hh < 4; ++hh) {
      const u16* qp = QKV + qrow * kQKVN + (kvg * 4 + hh) * 64 + lg * 8;
      qlo[hh] = *(const short8v*)qp;
      qhi[hh] = *(const short8v*)(qp + 32);
    }
    const u16* kb0 = QKV + (((long)b << 10) + w * 256 + lr) * kQKVN + 1024 + kvg * 64 + lg * 8;
    // pass 1: s = sum exp(score)
    float s[4][4] = {};
    for (int kt = 0; kt < 16; ++kt) {
      const u16* kp = kb0 + (long)kt * 16 * kQKVN;
      short8v klo = *(const short8v*)kp;
      short8v khi = *(const short8v*)(kp + 32);
      #pragma unroll
      for (int hh = 0; hh < 4; ++hh) {
        f32x4 c = {0.f, 0.f, 0.f, 0.f};
        c = MFMA16(qlo[hh], klo, c, 0, 0, 0);
        c = MFMA16(qhi[hh], khi, c, 0, 0, 0);
        #pragma unroll
        for (int i = 0; i < 4; ++i) s[hh][i] += __expf(c[i] * 0.125f);
      }
    }
    #pragma unroll
    for (int off = 1; off < 16; off <<= 1)
      #pragma unroll
      for (int hh = 0; hh < 4; ++hh)
        #pragma unroll
        for (int i = 0; i < 4; ++i) s[hh][i] += __shfl_xor(s[hh][i], off);
    __syncthreads();
    if (lr == 0)
      #pragma unroll
      for (int hh = 0; hh < 4; ++hh)
        #pragma unroll
        for (int i = 0; i < 4; ++i) sf[hh * 64 + w * 16 + lg * 4 + i] = s[hh][i];
    __syncthreads();
    float S[4][4];
    #pragma unroll
    for (int hh = 0; hh < 4; ++hh)
      #pragma unroll
      for (int i = 0; i < 4; ++i) {
        int q = lg * 4 + i;
        S[hh][i] = sf[hh * 64 + q] + sf[hh * 64 + 16 + q] + sf[hh * 64 + 32 + q] +
                   sf[hh * 64 + 48 + q];
      }
    // pass 2: thresholded sum (e > 0.01*S  <=>  aw > 0.01)
    float tt[4][4] = {};
    for (int kt = 0; kt < 16; ++kt) {
      const u16* kp = kb0 + (long)kt * 16 * kQKVN;
      short8v klo = *(const short8v*)kp;
      short8v khi = *(const short8v*)(kp + 32);
      #pragma unroll
      for (int hh = 0; hh < 4; ++hh) {
        f32x4 c = {0.f, 0.f, 0.f, 0.f};
        c = MFMA16(qlo[hh], klo, c, 0, 0, 0);
        c = MFMA16(qhi[hh], khi, c, 0, 0, 0);
        #pragma unroll
        for (int i = 0; i < 4; ++i) {
          float e = __expf(c[i] * 0.125f);
          if (e > 0.01f * S[hh][i]) tt[hh][i] += e;
        }
      }
    }
    #pragma unroll
    for (int off = 1; off < 16; off <<= 1)
      #pragma unroll
      for (int hh = 0; hh < 4; ++hh)
        #pragma unroll
        for (int i = 0; i < 4; ++i) tt[hh][i] += __shfl_xor(tt[hh][i], off);
    __syncthreads();
    if (lr == 0)
      #pragma unroll
      for (int hh = 0; hh < 4; ++hh)
        #pragma unroll
        for (int i = 0; i < 4; ++i) sf[256 + hh * 64 + w * 16 + lg * 4 + i] = tt[hh][i];
    __syncthreads();
    if (tid < 64) {
      int hh = tid >> 4, q = tid & 15;
      float T = sf[256 + hh * 64 + q] + sf[256 + hh * 64 + 16 + q] +
                sf[256 + hh * 64 + 32 + q] + sf[256 + hh * 64 + 48 + q];
      float Sq = sf[hh * 64 + q] + sf[hh * 64 + 16 + q] + sf[hh * 64 + 32 + q] +
                 sf[hh * 64 + 48 + q];
      sf[512 + hh * 16 + q] = T / Sq;
      if (T > 0.f) atomicOr(a_i + b, 1);
    }
    __syncthreads();
    {
      int hh = tid >> 6, rr = (tid >> 2) & 15, d0 = (tid & 3) * 16;
      float rv = sf[512 + hh * 16 + rr];
      long row = ((long)b << 10) + qt * 16 + rr;
      const u16* vp = QKV + row * kQKVN + 1280 + kvg * 64 + d0;
      u16* op = ATT + row * kH + (kvg * 4 + hh) * 64 + d0;
      #pragma unroll
      for (int j = 0; j < 16; j += 4) {
        ushort4 v = *(const ushort4*)(vp + j);
        ushort4 o;
        o.x = f2bf(rv * bf2f(v.x)); o.y = f2bf(rv * bf2f(v.y));
        o.z = f2bf(rv * bf2f(v.z)); o.w = f2bf(rv * bf2f(v.w));
        *(ushort4*)(op + j) = o;
      }
    }
  }
}

// ---------------- the mega kernel ----------------
__global__ __launch_bounds__(NTHR, 2) void mega_kernel(MegaArgs a) {
  cg::grid_group grid = cg::this_grid();
  const int tid = threadIdx.x;
  const int bid = blockIdx.x;
  const int nb = gridDim.x;

  float* ws = a.ws;
  float* h = ws + OFF_H;
  float* hm = ws + OFF_HM;
  int* ip = (int*)(ws + OFF_INT);
  float* gp = ws + OFF_GP;
  u16* slab = (u16*)(ws + OFF_SLAB);
  u16* woutbf = (u16*)(ws + OFF_WOUTBF);
  u16* hbf = (u16*)(ws + OFF_HBF);
  u16* QKV = (u16*)(ws + OFF_QKV);
  u16* ATT = (u16*)(ws + OFF_ATT);
  u16* Obf = (u16*)(ws + OFF_OBF);
  u16* Pbf = (u16*)(ws + OFF_PBF);

  __shared__ u16 sA[128 * 64];   // 16 KB
  __shared__ u16 sB[64 * 64];    // 8 KB
  __shared__ u16 sB1[64 * 64];   // 8 KB
  __shared__ float sf[768];      // 3 KB
  __shared__ int si[2];

  // ---- P1: per-block is_common flag (redundant, deterministic) + embed ----
  {
    int ok = 1;
    for (int i = tid; i < 2048; i += NTHR) ok &= (a.ids[i] < 1000) ? 1 : 0;
    if (tid == 0) si[0] = 1;
    __syncthreads();
    if (!ok) atomicAnd(&si[0], 0);
    __syncthreads();
    int common = si[0];
    #pragma unroll
    for (int j = 0; j < 4; ++j) {
      int row = bid * 4 + j;
      int id = a.ids[row];
      int cid = id < 0 ? 0 : (id > 999 ? 999 : id);
      const float4* s4 =
          (const float4*)(common ? a.semb + (long)cid * kH : a.emb + (long)id * kH);
      float4 v = s4[tid];
      *((float4*)(h + (long)row * kH) + tid) = v;
      ushort4 u;
      u.x = f2bf(v.x); u.y = f2bf(v.y); u.z = f2bf(v.z); u.w = f2bf(v.w);
      *((ushort4*)(hbf + (long)row * kH) + tid) = u;
    }
  }
  grid.sync();

  // ---- P2: hmean ----
  hmean_phase(h, hm);
  grid.sync();

  // ---- P3: per-block top-3 selection (redundant) ; gatevec + woutconv + act reset ----
  int sel0, sel1, sel2;
  {
    float acc0 = 0.f, acc1 = 0.f, acc2 = 0.f;
    for (int c = tid; c < kH; c += NTHR) {
      float hv = hm[c];
      acc0 += hv * a.Wls[c];
      acc1 += hv * a.Wls[kH + c];
      acc2 += hv * a.Wls[2 * kH + c];
    }
    sf[tid] = acc0; sf[256 + tid] = acc1; sf[512 + tid] = acc2;
    __syncthreads();
    for (int st = 128; st > 0; st >>= 1) {
      if (tid < st) {
        sf[tid] += sf[tid + st];
        sf[256 + tid] += sf[256 + tid + st];
        sf[512 + tid] += sf[512 + tid + st];
      }
      __syncthreads();
    }
    float scs[3];
    scs[0] = sf[0] * (1.f / kS) + a.bls[0];
    scs[1] = sf[256] * (1.f / kS) + a.bls[1];
    scs[2] = sf[512] * (1.f / kS) + a.bls[2];
    int aa = 0;
    if (scs[1] > scs[aa]) aa = 1;
    if (scs[2] > scs[aa]) aa = 2;
    int b2 = -1; float bb = -3.4e38f;
    for (int i = 0; i < 3; ++i)
      if (i != aa && scs[i] > bb) { bb = scs[i]; b2 = i; }
    sel0 = aa; sel1 = b2; sel2 = 3 - aa - b2;
    __syncthreads();
  }
  if (bid == 0 && tid < 6) ip[10 + tid] = 0;  // act reset, all layers
  {
    int selArr[3] = {sel0, sel1, sel2};
    for (int u = bid; u < 192 + 2560; u += nb) {
      if (u < 192) {
        int l = u >> 6, p = u & 63;
        const float* wq = a.Wq + (long)selArr[l] * (kH * kH) + (long)p * 16 * kH;
        float* partial = gp + (long)l * 65536 + (long)p * kH;
        float av[4] = {0.f, 0.f, 0.f, 0.f};
        for (int c = 0; c < 16; ++c) {
          float wb = a.Wbs[p * 16 + c];
          #pragma unroll
          for (int q = 0; q < 4; ++q) av[q] += wb * wq[(long)c * kH + tid + q * 256];
        }
        #pragma unroll
        for (int q = 0; q < 4; ++q) partial[tid + q * 256] = av[q];
      } else {
        long i = (long)(u - 192) * 1024 + tid * 4;
        float4 v = *(const float4*)(a.Wout + i);
        ushort4 o;
        o.x = f2bf(v.x); o.y = f2bf(v.y); o.z = f2bf(v.z); o.w = f2bf(v.w);
        *(ushort4*)(woutbf + i) = o;
      }
    }
  }
  grid.sync();

  // ---- layer loop ----
  bool h_zero = false;
  for (int l = 0; l < 3; ++l) {
    if (h_zero) continue;  // h==0: Q=0 -> aw=1/1024<0.01 -> attn=0 -> new_h=0 -> h stays 0
    int li = (l == 0) ? sel0 : (l == 1 ? sel1 : sel2);
    int* g_i = ip + 4 + 2 * l;
    int* a_i = ip + 10 + 2 * l;

    if (l > 0) {
      hmean_phase(h, hm);
      grid.sync();
    }
    // gatefin (block 0)
    if (bid == 0) {
      const float* partial = gp + (long)l * 65536;
      float a0 = 0.f, a1 = 0.f;
      for (int j = tid; j < kH; j += NTHR) {
        float v = 0.f;
        for (int p = 0; p < 64; ++p) v += partial[(long)p * kH + j];
        a0 += v * hm[j];
        a1 += v * hm[kH + j];
      }
      sf[tid] = a0; sf[256 + tid] = a1;
      __syncthreads();
      for (int st = 128; st > 0; st >>= 1) {
        if (tid < st) { sf[tid] += sf[tid + st]; sf[256 + tid] += sf[256 + tid + st]; }
        __syncthreads();
      }
      if (tid == 0) {
        g_i[0] = ((sf[0] * (1.f / kS) + a.bbs[0]) > 0.f) ? 1 : 0;
        g_i[1] = ((sf[256] * (1.f / kS) + a.bbs[0]) > 0.f) ? 1 : 0;
      }
    }
    grid.sync();
    int g0 = g_i[0], g1 = g_i[1];
    if (!g0 && !g1) continue;

    // wconv Wq|Wk|Wv
    for (int u = bid; u < 1536; u += nb) {
      long i = (long)u * 1024 + tid * 4;
      const float* src; long base, per;
      if (i < SB_WK)      { src = a.Wq; base = SB_WQ; per = 1048576; }
      else if (i < SB_WV) { src = a.Wk; base = SB_WK; per = 262144; }
      else                { src = a.Wv; base = SB_WV; per = 262144; }
      float4 v = *(const float4*)(src + (long)li * per + (i - base));
      ushort4 o;
      o.x = f2bf(v.x); o.y = f2bf(v.y); o.z = f2bf(v.z); o.w = f2bf(v.w);
      *(ushort4*)(slab + i) = o;
    }
    grid.sync();
    // QKV = h @ [Wq|Wk|Wv].T
    gemm_phase<0>(hbf, slab + SB_WQ, nullptr, QKV, nullptr, kQKVN, kH, 24,
                  g0, g1, 0, 0, sA, sB, sB1);
    grid.sync();
    // rowsum + attn
    rowsum_phase(QKV, g_i, a_i, ATT, sf);
    grid.sync();
    int ac0 = g0 && a_i[0], ac1 = g1 && a_i[1];
    if (!ac0 && !ac1) {
      // all attention thresholded out: new_h == 0 exactly for gated batches
      float4 z4 = make_float4(0.f, 0.f, 0.f, 0.f);
      ushort4 zu = {0, 0, 0, 0};
      for (int r = bid; r < 2048; r += nb) {
        if (!((r >> 10) ? g1 : g0)) continue;
        *((float4*)(h + (long)r * kH) + tid) = z4;
        *((ushort4*)(hbf + (long)r * kH) + tid) = zu;
      }
      grid.sync();
      if (g0 && g1) h_zero = true;
      continue;
    }
    // wconv Wo|Wg|Wu|Wd
    for (int u = bid; u < 13312; u += nb) {
      long i = SB_WO + (long)u * 1024 + tid * 4;
      const float* src; long base, per;
      if (i < SB_WG)      { src = a.Wo; base = SB_WO; per = 1048576; }
      else if (i < SB_WU) { src = a.Wg; base = SB_WG; per = 4194304; }
      else if (i < SB_WD) { src = a.Wu; base = SB_WU; per = 4194304; }
      else                { src = a.Wd; base = SB_WD; per = 4194304; }
      float4 v = *(const float4*)(src + (long)li * per + (i - base));
      ushort4 o;
      o.x = f2bf(v.x); o.y = f2bf(v.y); o.z = f2bf(v.z); o.w = f2bf(v.w);
      *(ushort4*)(slab + i) = o;
    }
    grid.sync();
    gemm_phase<0>(ATT, slab + SB_WO, nullptr, Obf, nullptr, kH, kH, 16,
                  ac0, ac1, 0, 0, sA, sB, sB1);
    grid.sync();
    gemm_phase<3>(Obf, slab + SB_WG, slab + SB_WU, Pbf, nullptr, kI, kH, 64,
                  ac0, ac1, 0, 0, sA, sB, sB1);
    grid.sync();
    gemm_phase<2>(Pbf, slab + SB_WD, nullptr, h, hbf, kH, kI, 16,
                  ac0, ac1, g0 && !a_i[0], g1 && !a_i[1], sA, sB, sB1);
    grid.sync();
    h_zero = false;
  }

  // ---- final: out = h @ Wout[:2560].T  (h==0 -> out==0 exactly) ----
  if (h_zero) {
    const long tot = (long)2048 * kNOUT / 4;
    float4 z4 = make_float4(0.f, 0.f, 0.f, 0.f);
    for (long i = (long)bid * NTHR + tid; i < tot; i += (long)nb * NTHR)
      *((float4*)a.out + i) = z4;
  } else {
    gemm_phase<1>(hbf, woutbf, nullptr, a.out, nullptr, kNOUT, kH, 40,
                  1, 1, 0, 0, sA, sB, sB1);
  }
}

// ---------------- launch ----------------
extern "C" void kernel_launch(void* const* d_in, const int* in_sizes, int n_in,
                              void* d_out, int out_size, void* d_ws, size_t ws_size,
                              hipStream_t stream) {
  (void)in_sizes; (void)n_in; (void)out_size; (void)ws_size;
  MegaArgs ma;
  ma.ids = (const int*)d_in[0];
  ma.emb = (const float*)d_in[1];
  ma.semb = (const float*)d_in[2];
  ma.Wq = (const float*)d_in[3];
  ma.Wk = (const float*)d_in[4];
  ma.Wv = (const float*)d_in[5];
  ma.Wo = (const float*)d_in[6];
  ma.Wg = (const float*)d_in[7];
  ma.Wu = (const float*)d_in[8];
  ma.Wd = (const float*)d_in[9];
  ma.Wls = (const float*)d_in[10];
  ma.bls = (const float*)d_in[11];
  ma.Wbs = (const float*)d_in[12];
  ma.bbs = (const float*)d_in[13];
  ma.Wout = (const float*)d_in[14];
  ma.out = (float*)d_out;
  ma.ws = (float*)d_ws;
  void* kargs[] = {&ma};
  hipLaunchCooperativeKernel((const void*)mega_kernel, dim3(NBLK), dim3(NTHR), kargs,
                             0, stream);
}

// Round 7
// 191.201 us; speedup vs baseline: 4.4303x; 4.4303x over previous
//
#include <hip/hip_runtime.h>
#include <hip/hip_bf16.h>

// ---------------- problem constants ----------------
constexpr int kH = 1024, kS = 1024, kNH = 16, kI = 4096, kNOUT = 2560;
constexpr int kQKVN = 1536;  // Q(1024)|K(256)|V(256)

typedef __attribute__((ext_vector_type(8))) short short8v;
typedef __attribute__((ext_vector_type(4))) float f32x4;
typedef unsigned short u16;

#define MFMA16 __builtin_amdgcn_mfma_f32_16x16x32_bf16

__device__ __forceinline__ u16 f2bf(float f) {
  unsigned u = __float_as_uint(f);
  return (u16)((u + 0x7fffu + ((u >> 16) & 1u)) >> 16);
}
__device__ __forceinline__ float bf2f(u16 u) {
  return __uint_as_float(((unsigned)u) << 16);
}
__device__ __forceinline__ void gload16(void* lds, const void* g) {
  __builtin_amdgcn_global_load_lds(
      (const __attribute__((address_space(1))) unsigned int*)g,
      (__attribute__((address_space(3))) unsigned int*)lds, 16, 0, 0);
}

// ---------------- workspace layout (float offsets) ----------------
constexpr long OFF_H      = 0;                        // 2048x1024 f32
constexpr long OFF_HMP    = OFF_H + 2097152;          // hmean partials [8][2048]
constexpr long OFF_INT    = OFF_HMP + 16384;          // [1..3] sel [4..9] gate [10..15] act [16..17] hzb
constexpr long OFF_GP     = OFF_INT + 64;             // [3][64][1024]
constexpr long OFF_SLAB   = OFF_GP + 196608;          // 15,204,352 bf16
constexpr long OFF_WOUTBF = OFF_SLAB + 7602176;       // 2560x1024 bf16
constexpr long OFF_HBF    = OFF_WOUTBF + 1310720;     // 2048x1024 bf16
constexpr long OFF_QKV    = OFF_HBF + 1048576;        // 2048x1536 bf16
constexpr long OFF_ATT    = OFF_QKV + 1572864;        // 2048x1024 bf16
constexpr long OFF_OBF    = OFF_ATT + 1048576;        // 2048x1024 bf16
constexpr long OFF_PBF    = OFF_OBF + 1048576;        // 2048x4096 bf16

constexpr long SB_WQ = 0, SB_WK = 1048576, SB_WV = 1310720, SB_WO = 1572864,
               SB_WG = 2621440, SB_WU = 6815744, SB_WD = 11010048, SB_TOT = 15204352;

// ---------------- embed (+ per-block is_common flag) ----------------
__global__ void embed_kernel(const int* __restrict__ ids, const float* __restrict__ emb,
                             const float* __restrict__ semb, float* __restrict__ h,
                             u16* __restrict__ hbf) {
  __shared__ int oks;
  int tid = threadIdx.x;
  if (tid == 0) oks = 1;
  __syncthreads();
  int ok = 1;
  for (int i = tid; i < 2048; i += 256) ok &= (ids[i] < 1000) ? 1 : 0;
  if (!ok) atomicAnd(&oks, 0);
  __syncthreads();
  int common = oks;
  long row = blockIdx.x;
  int id = ids[row];
  int cid = id < 0 ? 0 : (id > 999 ? 999 : id);
  const float4* s4 = (const float4*)(common ? semb + (long)cid * kH : emb + (long)id * kH);
  float4 v = s4[tid];
  *((float4*)(h + row * kH) + tid) = v;
  ushort4 u;
  u.x = f2bf(v.x); u.y = f2bf(v.y); u.z = f2bf(v.z); u.w = f2bf(v.w);
  *((ushort4*)(hbf + row * kH) + tid) = u;
}

// ---------------- hmean partials: grid (4, 2, 8) -> hmp[z][b*1024+c] ----------------
__global__ void hmean_kernel(const float* __restrict__ h, float* __restrict__ hmp) {
  int c = blockIdx.x * 256 + threadIdx.x;
  int b = blockIdx.y, z = blockIdx.z;
  const float* p = h + ((long)b << 20) + ((long)z << 17) + c;  // z*128 rows * 1024
  float a = 0.f;
  #pragma unroll 4
  for (int r = 0; r < 128; ++r) a += p[(long)r << 10];
  hmp[z * 2048 + b * 1024 + c] = a;
}

// ---------------- scores + top-3 + per-launch flag resets ----------------
__global__ void scores_kernel(const float* __restrict__ hmp, const float* __restrict__ Wls,
                              const float* __restrict__ bls, int* __restrict__ ip) {
  __shared__ float s0[256], s1[256], s2[256];
  int tid = threadIdx.x;
  float a0 = 0.f, a1 = 0.f, a2 = 0.f;
  for (int c = tid; c < kH; c += 256) {
    float hv = 0.f;
    #pragma unroll
    for (int z = 0; z < 8; ++z) hv += hmp[z * 2048 + c];
    a0 += hv * Wls[c]; a1 += hv * Wls[kH + c]; a2 += hv * Wls[2 * kH + c];
  }
  s0[tid] = a0; s1[tid] = a1; s2[tid] = a2;
  __syncthreads();
  for (int st = 128; st; st >>= 1) {
    if (tid < st) { s0[tid] += s0[tid + st]; s1[tid] += s1[tid + st]; s2[tid] += s2[tid + st]; }
    __syncthreads();
  }
  if (tid == 0) {
    float sc[3] = {s0[0] * (1.f / kS) + bls[0], s1[0] * (1.f / kS) + bls[1],
                   s2[0] * (1.f / kS) + bls[2]};
    int aa = 0;
    if (sc[1] > sc[aa]) aa = 1;
    if (sc[2] > sc[aa]) aa = 2;
    int b2 = -1; float bb = -3.4e38f;
    for (int i = 0; i < 3; ++i)
      if (i != aa && sc[i] > bb) { bb = sc[i]; b2 = i; }
    ip[1] = aa; ip[2] = b2; ip[3] = 3 - aa - b2;
    for (int q = 0; q < 6; ++q) ip[10 + q] = 0;  // act
    ip[16] = 0; ip[17] = 0;                      // hzb
  }
}

// ---------------- prep2: gatevec (192 blocks) + Wout->bf16 (2560 blocks) -------------
__global__ void prep2_kernel(const float* __restrict__ Wq, const int* __restrict__ ip,
                             const float* __restrict__ Wbs, float* __restrict__ gp,
                             const float* __restrict__ Wout, u16* __restrict__ woutbf) {
  int bid = blockIdx.x, tid = threadIdx.x;
  if (bid < 192) {
    int l = bid >> 6, p = bid & 63;
    const float* wq = Wq + (long)ip[1 + l] * (kH * kH) + (long)p * 16 * kH;
    float* partial = gp + (long)l * 65536 + (long)p * kH;
    float acc[4] = {0.f, 0.f, 0.f, 0.f};
    for (int c = 0; c < 16; ++c) {
      float wb = Wbs[p * 16 + c];
      #pragma unroll
      for (int u = 0; u < 4; ++u) acc[u] += wb * wq[(long)c * kH + tid + u * 256];
    }
    #pragma unroll
    for (int u = 0; u < 4; ++u) partial[tid + u * 256] = acc[u];
  } else {
    long i = (long)(bid - 192) * 1024 + tid * 4;
    float4 v = *(const float4*)(Wout + i);
    ushort4 o;
    o.x = f2bf(v.x); o.y = f2bf(v.y); o.z = f2bf(v.z); o.w = f2bf(v.w);
    *(ushort4*)(woutbf + i) = o;
  }
}

// ---------------- gatefin: g[b] = (dot(hm_b, v)/S + bbs > 0) ----------------
__global__ void gatefin_kernel(const float* __restrict__ hmp, const float* __restrict__ partial,
                               const float* __restrict__ bbs, int* __restrict__ g) {
  __shared__ float r0[256], r1[256];
  int tid = threadIdx.x;
  float a0 = 0.f, a1 = 0.f;
  for (int j = tid; j < kH; j += 256) {
    float v = 0.f;
    for (int p = 0; p < 64; ++p) v += partial[(long)p * kH + j];
    float h0 = 0.f, h1 = 0.f;
    #pragma unroll
    for (int z = 0; z < 8; ++z) { h0 += hmp[z * 2048 + j]; h1 += hmp[z * 2048 + kH + j]; }
    a0 += v * h0; a1 += v * h1;
  }
  r0[tid] = a0; r1[tid] = a1;
  __syncthreads();
  for (int st = 128; st; st >>= 1) {
    if (tid < st) { r0[tid] += r0[tid + st]; r1[tid] += r1[tid + st]; }
    __syncthreads();
  }
  if (tid == 0) {
    g[0] = ((r0[0] * (1.f / kS) + bbs[0]) > 0.f) ? 1 : 0;
    g[1] = ((r1[0] * (1.f / kS) + bbs[0]) > 0.f) ? 1 : 0;
  }
}

// ---------------- weight conversion: Wq|Wk|Wv ----------------
__global__ void wconvqkv_kernel(const float* __restrict__ Wq, const float* __restrict__ Wk,
                                const float* __restrict__ Wv, const int* __restrict__ li_p,
                                const int* __restrict__ gate, u16* __restrict__ slab) {
  if (!gate[0] && !gate[1]) return;
  long i = ((long)blockIdx.x * 256 + threadIdx.x) * 4;
  int li = *li_p;
  const float* src; long base, per;
  if      (i < SB_WK) { src = Wq; base = SB_WQ; per = 1048576; }
  else if (i < SB_WV) { src = Wk; base = SB_WK; per = 262144;  }
  else                { src = Wv; base = SB_WV; per = 262144;  }
  float4 v = *(const float4*)(src + (long)li * per + (i - base));
  ushort4 o;
  o.x = f2bf(v.x); o.y = f2bf(v.y); o.z = f2bf(v.z); o.w = f2bf(v.w);
  *(ushort4*)(slab + i) = o;
}

// ---------------- weight conversion: Wo|Wg|Wu|Wd (only if attention fired) ----------
__global__ void wconvrest_kernel(const float* __restrict__ Wo, const float* __restrict__ Wg,
                                 const float* __restrict__ Wu, const float* __restrict__ Wd,
                                 const int* __restrict__ li_p, const int* __restrict__ gate,
                                 const int* __restrict__ act, u16* __restrict__ slab) {
  if (!((gate[0] && act[0]) || (gate[1] && act[1]))) return;
  int li = *li_p;
  const long step = (long)gridDim.x * 256 * 4;
  for (long i = SB_WO + ((long)blockIdx.x * 256 + threadIdx.x) * 4; i < SB_TOT; i += step) {
    const float* src; long base, per;
    if      (i < SB_WG) { src = Wo; base = SB_WO; per = 1048576; }
    else if (i < SB_WU) { src = Wg; base = SB_WG; per = 4194304; }
    else if (i < SB_WD) { src = Wu; base = SB_WU; per = 4194304; }
    else                { src = Wd; base = SB_WD; per = 4194304; }
    float4 v = *(const float4*)(src + (long)li * per + (i - base));
    ushort4 o;
    o.x = f2bf(v.x); o.y = f2bf(v.y); o.z = f2bf(v.z); o.w = f2bf(v.w);
    *(ushort4*)(slab + i) = o;
  }
}

// ---------------- bf16 MFMA GEMM: C = A @ B.T ----------------
// MODE 0: bf16 out. 1: f32 out (+hz per-batch zero-fill). 2: f32 C0 + bf16 C1
//         (+act zfill, +hzb maintenance). 3: dual-B, bf16 out = acc0*acc1.
template <int MODE>
__global__ __launch_bounds__(256) void gemm_bf_kernel(
    const u16* __restrict__ A, const u16* __restrict__ B0, const u16* __restrict__ B1,
    void* __restrict__ C0, void* __restrict__ C1, int M, int N, int K,
    const int* __restrict__ gate, const int* __restrict__ act,
    int* __restrict__ hzwr, const int* __restrict__ hz) {
  constexpr bool USE_B1 = (MODE == 3);
  constexpr int BM = 128, BN = 64, BK = 64;
  __shared__ u16 As[BM * BK];
  __shared__ u16 Bs[BN * BK];
  __shared__ u16 Bs1[USE_B1 ? BN * BK : 8];

  const int m0 = blockIdx.y * BM, n0 = blockIdx.x * BN;
  const int tid = threadIdx.x;
  const int bb = m0 >> 10;  // 128 | 1024: batch-pure blocks

  if (MODE == 1 && hz != nullptr && hz[bb]) {  // h rows are exactly 0 -> out rows 0
    int r = tid >> 1, cb = n0 + (tid & 1) * 32;
    float* c0 = (float*)C0 + (long)(m0 + r) * N + cb;
    float4 z4 = make_float4(0.f, 0.f, 0.f, 0.f);
    #pragma unroll
    for (int j = 0; j < 32; j += 4) *(float4*)(c0 + j) = z4;
    return;
  }
  if (gate != nullptr) {
    int g = gate[bb];
    int ac = (act != nullptr) ? act[bb] : 1;
    if (MODE == 2 && hzwr != nullptr && tid == 0 && blockIdx.x == 0 && (m0 & 1023) == 0) {
      if (g && ac) hzwr[bb] = 0;
      else if (g && !ac) hzwr[bb] = 1;
    }
    if (!g) return;
    if (!ac) {
      if constexpr (MODE == 2) {  // new_h == 0 exactly
        int r = tid >> 1, cb = n0 + (tid & 1) * 32;
        float* c0 = (float*)C0 + (long)(m0 + r) * N + cb;
        u16* c1 = (u16*)C1 + (long)(m0 + r) * N + cb;
        float4 z4 = make_float4(0.f, 0.f, 0.f, 0.f);
        ushort4 zu = {0, 0, 0, 0};
        #pragma unroll
        for (int j = 0; j < 32; j += 4) { *(float4*)(c0 + j) = z4; *(ushort4*)(c1 + j) = zu; }
      }
      return;
    }
  }

  const int wave = tid >> 6, lane = tid & 63;
  const int lr = lane & 15, lg = lane >> 4;
  const int wm = wave >> 1, wn = wave & 1;

  f32x4 acc[4][2] = {};
  f32x4 acc1[USE_B1 ? 4 : 1][2] = {};

  for (int k0 = 0; k0 < K; k0 += BK) {
    #pragma unroll
    for (int j = 0; j < 4; ++j) {
      int c = tid + j * 256;
      int r = c >> 3, c8 = c & 7;
      gload16((char*)As + (wave * 64 + j * 256) * 16,
              A + (long)(m0 + r) * K + k0 + ((c8 ^ (r & 7)) * 8));
    }
    #pragma unroll
    for (int j = 0; j < 2; ++j) {
      int c = tid + j * 256;
      int r = c >> 3, c8 = c & 7;
      long gb = (long)(n0 + r) * K + k0 + ((c8 ^ (r & 7)) * 8);
      gload16((char*)Bs + (wave * 64 + j * 256) * 16, B0 + gb);
      if constexpr (USE_B1)
        gload16((char*)Bs1 + (wave * 64 + j * 256) * 16, B1 + gb);
    }
    __syncthreads();
    #pragma unroll
    for (int kh = 0; kh < 2; ++kh) {
      const int kb = kh * 64 + lg * 16;
      short8v av[4], bv[2], b1v[2];
      #pragma unroll
      for (int mi = 0; mi < 4; ++mi) {
        int r = wm * 64 + mi * 16 + lr;
        av[mi] = *(const short8v*)((const char*)As + ((r * 128 + kb) ^ ((r & 7) << 4)));
      }
      #pragma unroll
      for (int ni = 0; ni < 2; ++ni) {
        int r = wn * 32 + ni * 16 + lr;
        int byte = (r * 128 + kb) ^ ((r & 7) << 4);
        bv[ni] = *(const short8v*)((const char*)Bs + byte);
        if constexpr (USE_B1) b1v[ni] = *(const short8v*)((const char*)Bs1 + byte);
      }
      #pragma unroll
      for (int mi = 0; mi < 4; ++mi)
        #pragma unroll
        for (int ni = 0; ni < 2; ++ni) {
          acc[mi][ni] = MFMA16(av[mi], bv[ni], acc[mi][ni], 0, 0, 0);
          if constexpr (USE_B1)
            acc1[mi][ni] = MFMA16(av[mi], b1v[ni], acc1[mi][ni], 0, 0, 0);
        }
    }
    __syncthreads();
  }
  #pragma unroll
  for (int mi = 0; mi < 4; ++mi)
    #pragma unroll
    for (int ni = 0; ni < 2; ++ni)
      #pragma unroll
      for (int r = 0; r < 4; ++r) {
        long idx = (long)(m0 + wm * 64 + mi * 16 + lg * 4 + r) * N +
                   (n0 + wn * 32 + ni * 16 + lr);
        float v = acc[mi][ni][r];
        if constexpr (MODE == 0) ((u16*)C0)[idx] = f2bf(v);
        if constexpr (MODE == 1) ((float*)C0)[idx] = v;
        if constexpr (MODE == 2) { ((float*)C0)[idx] = v; ((u16*)C1)[idx] = f2bf(v); }
        if constexpr (MODE == 3) ((u16*)C0)[idx] = f2bf(v * acc1[mi][ni][r]);
      }
}

// ---------------- rowsum(thresholded softmax) + fused attn = rs*V ----------------
// grid (64, 4, 2): 16 q-rows x 4 heads of one kv-group per block; 4 waves split k-range.
// Online max; pass 2 skipped block-uniformly when no row can pass (S_rel >= 100).
__global__ __launch_bounds__(256) void rowsum_kernel(
    const u16* __restrict__ QKV, const int* __restrict__ gate, int* __restrict__ act,
    u16* __restrict__ ATT) {
  int b = blockIdx.z;
  if (!gate[b]) return;
  int kvg = blockIdx.y, qt = blockIdx.x;
  int tid = threadIdx.x;
  int w = tid >> 6, lane = tid & 63, lr = lane & 15, lg = lane >> 4;

  __shared__ float sm[4][64], ss[4][64], st[4][64], srs[64];
  __shared__ int sskip;
  if (tid == 0) sskip = 0;

  long qrow = ((long)b << 10) + qt * 16 + lr;
  short8v qlo[4], qhi[4];
  #pragma unroll
  for (int hh = 0; hh < 4; ++hh) {
    const u16* qp = QKV + qrow * kQKVN + (kvg * 4 + hh) * 64 + lg * 8;
    qlo[hh] = *(const short8v*)qp;
    qhi[hh] = *(const short8v*)(qp + 32);
  }
  const u16* kb0 = QKV + (((long)b << 10) + w * 256 + lr) * kQKVN + 1024 + kvg * 64 + lg * 8;

  // pass 1: online max + denominator over this wave's 256 k-rows
  float m[4][4], s[4][4];
  #pragma unroll
  for (int hh = 0; hh < 4; ++hh)
    #pragma unroll
    for (int i = 0; i < 4; ++i) { m[hh][i] = -3e38f; s[hh][i] = 0.f; }
  for (int kt = 0; kt < 16; ++kt) {
    const u16* kp = kb0 + (long)kt * 16 * kQKVN;
    short8v klo = *(const short8v*)kp;
    short8v khi = *(const short8v*)(kp + 32);
    #pragma unroll
    for (int hh = 0; hh < 4; ++hh) {
      f32x4 c = {0.f, 0.f, 0.f, 0.f};
      c = MFMA16(qlo[hh], klo, c, 0, 0, 0);
      c = MFMA16(qhi[hh], khi, c, 0, 0, 0);
      #pragma unroll
      for (int i = 0; i < 4; ++i) {
        float x = c[i] * 0.125f;
        if (x > m[hh][i]) { s[hh][i] = s[hh][i] * __expf(m[hh][i] - x) + 1.f; m[hh][i] = x; }
        else s[hh][i] += __expf(x - m[hh][i]);
      }
    }
  }
  #pragma unroll
  for (int off = 1; off < 16; off <<= 1)
    #pragma unroll
    for (int hh = 0; hh < 4; ++hh)
      #pragma unroll
      for (int i = 0; i < 4; ++i) {
        float mo = __shfl_xor(m[hh][i], off);
        float so = __shfl_xor(s[hh][i], off);
        float mn = fmaxf(m[hh][i], mo);
        s[hh][i] = s[hh][i] * __expf(m[hh][i] - mn) + so * __expf(mo - mn);
        m[hh][i] = mn;
      }
  if (lr == 0)
    #pragma unroll
    for (int hh = 0; hh < 4; ++hh)
      #pragma unroll
      for (int i = 0; i < 4; ++i) { sm[w][hh * 16 + lg * 4 + i] = m[hh][i]; ss[w][hh * 16 + lg * 4 + i] = s[hh][i]; }
  __syncthreads();
  // merged stats per (hh, q)
  float Mg[4][4], Sg[4][4];
  int need = 0;
  #pragma unroll
  for (int hh = 0; hh < 4; ++hh)
    #pragma unroll
    for (int i = 0; i < 4; ++i) {
      int q = hh * 16 + lg * 4 + i;
      float mm = fmaxf(fmaxf(sm[0][q], sm[1][q]), fmaxf(sm[2][q], sm[3][q]));
      float SS = ss[0][q] * __expf(sm[0][q] - mm) + ss[1][q] * __expf(sm[1][q] - mm) +
                 ss[2][q] * __expf(sm[2][q] - mm) + ss[3][q] * __expf(sm[3][q] - mm);
      Mg[hh][i] = mm; Sg[hh][i] = SS;
      need |= (SS < 100.f) ? 1 : 0;  // max elem survives iff 1 > 0.01*S
    }
  if (need) atomicOr(&sskip, 1);
  __syncthreads();
  int do2 = sskip;
  if (do2) {
    float tt[4][4] = {};
    for (int kt = 0; kt < 16; ++kt) {
      const u16* kp = kb0 + (long)kt * 16 * kQKVN;
      short8v klo = *(const short8v*)kp;
      short8v khi = *(const short8v*)(kp + 32);
      #pragma unroll
      for (int hh = 0; hh < 4; ++hh) {
        f32x4 c = {0.f, 0.f, 0.f, 0.f};
        c = MFMA16(qlo[hh], klo, c, 0, 0, 0);
        c = MFMA16(qhi[hh], khi, c, 0, 0, 0);
        #pragma unroll
        for (int i = 0; i < 4; ++i) {
          float e = __expf(c[i] * 0.125f - Mg[hh][i]);
          if (e > 0.01f * Sg[hh][i]) tt[hh][i] += e;
        }
      }
    }
    #pragma unroll
    for (int off = 1; off < 16; off <<= 1)
      #pragma unroll
      for (int hh = 0; hh < 4; ++hh)
        #pragma unroll
        for (int i = 0; i < 4; ++i) tt[hh][i] += __shfl_xor(tt[hh][i], off);
    if (lr == 0)
      #pragma unroll
      for (int hh = 0; hh < 4; ++hh)
        #pragma unroll
        for (int i = 0; i < 4; ++i) st[w][hh * 16 + lg * 4 + i] = tt[hh][i];
  }
  __syncthreads();
  if (tid < 64) {
    int hh = tid >> 4, q = tid & 15;
    float T = do2 ? (st[0][hh * 16 + q] + st[1][hh * 16 + q] + st[2][hh * 16 + q] +
                     st[3][hh * 16 + q])
                  : 0.f;
    float mm = fmaxf(fmaxf(sm[0][hh * 16 + q], sm[1][hh * 16 + q]),
                     fmaxf(sm[2][hh * 16 + q], sm[3][hh * 16 + q]));
    float SS = ss[0][hh * 16 + q] * __expf(sm[0][hh * 16 + q] - mm) +
               ss[1][hh * 16 + q] * __expf(sm[1][hh * 16 + q] - mm) +
               ss[2][hh * 16 + q] * __expf(sm[2][hh * 16 + q] - mm) +
               ss[3][hh * 16 + q] * __expf(sm[3][hh * 16 + q] - mm);
    srs[hh * 16 + q] = T / SS;
    if (T > 0.f) atomicOr(act + b, 1);
  }
  __syncthreads();
  // fused attn write: ATT[row][(kvg*4+hh)*64 + d] = rs * V[row][kvg*64 + d]
  int hh = tid >> 6, rr = (tid >> 2) & 15, d0 = (tid & 3) * 16;
  float rv = srs[hh * 16 + rr];
  long row = ((long)b << 10) + qt * 16 + rr;
  const u16* vp = QKV + row * kQKVN + 1280 + kvg * 64 + d0;
  u16* op = ATT + row * kH + (kvg * 4 + hh) * 64 + d0;
  #pragma unroll
  for (int j = 0; j < 16; j += 4) {
    ushort4 v = *(const ushort4*)(vp + j);
    ushort4 o;
    o.x = f2bf(rv * bf2f(v.x)); o.y = f2bf(rv * bf2f(v.y));
    o.z = f2bf(rv * bf2f(v.z)); o.w = f2bf(rv * bf2f(v.w));
    *(ushort4*)(op + j) = o;
  }
}

// ---------------- launch ----------------
extern "C" void kernel_launch(void* const* d_in, const int* in_sizes, int n_in,
                              void* d_out, int out_size, void* d_ws, size_t ws_size,
                              hipStream_t stream) {
  (void)in_sizes; (void)n_in; (void)out_size; (void)ws_size;
  const int*   ids  = (const int*)d_in[0];
  const float* emb  = (const float*)d_in[1];
  const float* semb = (const float*)d_in[2];
  const float* Wq   = (const float*)d_in[3];
  const float* Wk   = (const float*)d_in[4];
  const float* Wv   = (const float*)d_in[5];
  const float* Wo   = (const float*)d_in[6];
  const float* Wg   = (const float*)d_in[7];
  const float* Wu   = (const float*)d_in[8];
  const float* Wd   = (const float*)d_in[9];
  const float* Wls  = (const float*)d_in[10];
  const float* bls  = (const float*)d_in[11];
  const float* Wbs  = (const float*)d_in[12];
  const float* bbs  = (const float*)d_in[13];
  const float* Wout = (const float*)d_in[14];
  float* out = (float*)d_out;
  float* ws  = (float*)d_ws;

  float* h   = ws + OFF_H;
  float* hmp = ws + OFF_HMP;
  int* ip    = (int*)(ws + OFF_INT);
  int* sel   = ip + 1;
  int* gate  = ip + 4;
  int* act   = ip + 10;
  int* hzb   = ip + 16;
  float* gp  = ws + OFF_GP;
  u16* slab   = (u16*)(ws + OFF_SLAB);
  u16* woutbf = (u16*)(ws + OFF_WOUTBF);
  u16* hbf    = (u16*)(ws + OFF_HBF);
  u16* QKV    = (u16*)(ws + OFF_QKV);
  u16* ATT    = (u16*)(ws + OFF_ATT);
  u16* Obf    = (u16*)(ws + OFF_OBF);
  u16* Pbf    = (u16*)(ws + OFF_PBF);

  const int M = 2048;

  embed_kernel<<<M, 256, 0, stream>>>(ids, emb, semb, h, hbf);
  hmean_kernel<<<dim3(4, 2, 8), 256, 0, stream>>>(h, hmp);
  scores_kernel<<<1, 256, 0, stream>>>(hmp, Wls, bls, ip);
  prep2_kernel<<<192 + 2560, 256, 0, stream>>>(Wq, ip, Wbs, gp, Wout, woutbf);

  for (int i = 0; i < 3; i++) {
    const int* li = sel + i;
    int* g_i = gate + 2 * i;
    int* a_i = act + 2 * i;

    if (i > 0) hmean_kernel<<<dim3(4, 2, 8), 256, 0, stream>>>(h, hmp);
    gatefin_kernel<<<1, 256, 0, stream>>>(hmp, gp + (long)i * 65536, bbs, g_i);
    wconvqkv_kernel<<<1536, 256, 0, stream>>>(Wq, Wk, Wv, li, g_i, slab);
    // QKV = h @ [Wq|Wk|Wv].T
    gemm_bf_kernel<0><<<dim3(kQKVN / 64, 16), 256, 0, stream>>>(
        hbf, slab + SB_WQ, nullptr, QKV, nullptr, M, kQKVN, kH, g_i, nullptr, nullptr, nullptr);
    // thresholded-softmax rowsum + attn (sets act)
    rowsum_kernel<<<dim3(64, 4, 2), 256, 0, stream>>>(QKV, g_i, a_i, ATT);
    wconvrest_kernel<<<2048, 256, 0, stream>>>(Wo, Wg, Wu, Wd, li, g_i, a_i, slab);
    // O = attn @ wo.T
    gemm_bf_kernel<0><<<dim3(kH / 64, 16), 256, 0, stream>>>(
        ATT, slab + SB_WO, nullptr, Obf, nullptr, M, kH, kH, g_i, a_i, nullptr, nullptr);
    // P = (O @ wg.T) * (O @ wu.T)
    gemm_bf_kernel<3><<<dim3(kI / 64, 16), 256, 0, stream>>>(
        Obf, slab + SB_WG, slab + SB_WU, Pbf, nullptr, M, kI, kH, g_i, a_i, nullptr, nullptr);
    // h = P @ wd.T -> f32 h + bf16 hbf; zero-fill + hzb maintenance
    gemm_bf_kernel<2><<<dim3(kH / 64, 16), 256, 0, stream>>>(
        Pbf, slab + SB_WD, nullptr, h, hbf, M, kH, kI, g_i, a_i, hzb, nullptr);
  }
  // out = h @ Wout[:2560].T (per-batch zero fast path when h==0)
  gemm_bf_kernel<1><<<dim3(kNOUT / 64, 16), 256, 0, stream>>>(
      hbf, woutbf, nullptr, out, nullptr, M, kNOUT, kH, nullptr, nullptr, nullptr, hzb);
}

// Round 8
// 175.868 us; speedup vs baseline: 4.8166x; 1.0872x over previous
//
#include <hip/hip_runtime.h>
#include <hip/hip_bf16.h>

// ---------------- problem constants ----------------
constexpr int kH = 1024, kS = 1024, kNH = 16, kI = 4096, kNOUT = 2560;
constexpr int kQKVN = 1536;  // Q(1024)|K(256)|V(256)

typedef __attribute__((ext_vector_type(8))) short short8v;
typedef __attribute__((ext_vector_type(4))) float f32x4;
typedef unsigned short u16;

#define MFMA16 __builtin_amdgcn_mfma_f32_16x16x32_bf16

__device__ __forceinline__ u16 f2bf(float f) {
  unsigned u = __float_as_uint(f);
  return (u16)((u + 0x7fffu + ((u >> 16) & 1u)) >> 16);
}
__device__ __forceinline__ float bf2f(u16 u) {
  return __uint_as_float(((unsigned)u) << 16);
}
__device__ __forceinline__ void gload16(void* lds, const void* g) {
  __builtin_amdgcn_global_load_lds(
      (const __attribute__((address_space(1))) unsigned int*)g,
      (__attribute__((address_space(3))) unsigned int*)lds, 16, 0, 0);
}

// ---------------- workspace layout (float offsets) ----------------
constexpr long OFF_H    = 0;                        // 2048x1024 f32
constexpr long OFF_HMP  = OFF_H + 2097152;          // hmean partials [8][2048]
constexpr long OFF_INT  = OFF_HMP + 16384;          // [1..3] sel [4..9] gate [10..15] act [16..17] hzb
constexpr long OFF_GP   = OFF_INT + 64;             // [3][64][1024] physical-layer gate partials
constexpr long OFF_HBF  = OFF_GP + 196608;          // 2048x1024 bf16
constexpr long OFF_QKV  = OFF_HBF + 1048576;        // 2048x1536 bf16
constexpr long OFF_ATT  = OFF_QKV + 1572864;        // 2048x1024 bf16
constexpr long OFF_OBF  = OFF_ATT + 1048576;        // 2048x1024 bf16
constexpr long OFF_PBF  = OFF_OBF + 1048576;        // 2048x4096 bf16

// ---------------- embed (+ per-block is_common flag) + gatevec (physical layers) -----
// blocks [0,2048): embed row; blocks [2048,2240): gatevec for layer l=(b-2048)>>6.
__global__ void embed_gv_kernel(const int* __restrict__ ids, const float* __restrict__ emb,
                                const float* __restrict__ semb, const float* __restrict__ Wq,
                                const float* __restrict__ Wbs, float* __restrict__ h,
                                u16* __restrict__ hbf, float* __restrict__ gp) {
  int bid = blockIdx.x, tid = threadIdx.x;
  if (bid < 2048) {
    __shared__ int oks;
    if (tid == 0) oks = 1;
    __syncthreads();
    int ok = 1;
    for (int i = tid; i < 2048; i += 256) ok &= (ids[i] < 1000) ? 1 : 0;
    if (!ok) atomicAnd(&oks, 0);
    __syncthreads();
    int common = oks;
    long row = bid;
    int id = ids[row];
    int cid = id < 0 ? 0 : (id > 999 ? 999 : id);
    const float4* s4 = (const float4*)(common ? semb + (long)cid * kH : emb + (long)id * kH);
    float4 v = s4[tid];
    *((float4*)(h + row * kH) + tid) = v;
    ushort4 u;
    u.x = f2bf(v.x); u.y = f2bf(v.y); u.z = f2bf(v.z); u.w = f2bf(v.w);
    *((ushort4*)(hbf + row * kH) + tid) = u;
  } else {
    int q = bid - 2048;           // 0..191
    int l = q >> 6, p = q & 63;   // physical layer l (sel is a permutation of {0,1,2})
    const float* wq = Wq + (long)l * 1048576 + (long)p * 16 * kH;
    float* partial = gp + (long)l * 65536 + (long)p * kH;
    float acc[4] = {0.f, 0.f, 0.f, 0.f};
    for (int c = 0; c < 16; ++c) {
      float wb = Wbs[p * 16 + c];
      #pragma unroll
      for (int u = 0; u < 4; ++u) acc[u] += wb * wq[(long)c * kH + tid + u * 256];
    }
    #pragma unroll
    for (int u = 0; u < 4; ++u) partial[tid + u * 256] = acc[u];
  }
}

// ---------------- hmean partials: grid (4, 2, 8) -> hmp[z][b*1024+c] ----------------
__global__ void hmean_kernel(const float* __restrict__ h, float* __restrict__ hmp) {
  int c = blockIdx.x * 256 + threadIdx.x;
  int b = blockIdx.y, z = blockIdx.z;
  const float* p = h + ((long)b << 20) + ((long)z << 17) + c;
  float a = 0.f;
  #pragma unroll 4
  for (int r = 0; r < 128; ++r) a += p[(long)r << 10];
  hmp[z * 2048 + b * 1024 + c] = a;
}

// ---------------- scores + top-3 + per-launch flag resets ----------------
__global__ void scores_kernel(const float* __restrict__ hmp, const float* __restrict__ Wls,
                              const float* __restrict__ bls, int* __restrict__ ip) {
  __shared__ float s0[256], s1[256], s2[256];
  int tid = threadIdx.x;
  float a0 = 0.f, a1 = 0.f, a2 = 0.f;
  for (int c = tid; c < kH; c += 256) {
    float hv = 0.f;
    #pragma unroll
    for (int z = 0; z < 8; ++z) hv += hmp[z * 2048 + c];
    a0 += hv * Wls[c]; a1 += hv * Wls[kH + c]; a2 += hv * Wls[2 * kH + c];
  }
  s0[tid] = a0; s1[tid] = a1; s2[tid] = a2;
  __syncthreads();
  for (int st = 128; st; st >>= 1) {
    if (tid < st) { s0[tid] += s0[tid + st]; s1[tid] += s1[tid + st]; s2[tid] += s2[tid + st]; }
    __syncthreads();
  }
  if (tid == 0) {
    float sc[3] = {s0[0] * (1.f / kS) + bls[0], s1[0] * (1.f / kS) + bls[1],
                   s2[0] * (1.f / kS) + bls[2]};
    int aa = 0;
    if (sc[1] > sc[aa]) aa = 1;
    if (sc[2] > sc[aa]) aa = 2;
    int b2 = -1; float bb = -3.4e38f;
    for (int i = 0; i < 3; ++i)
      if (i != aa && sc[i] > bb) { bb = sc[i]; b2 = i; }
    ip[1] = aa; ip[2] = b2; ip[3] = 3 - aa - b2;
    for (int q = 0; q < 6; ++q) ip[10 + q] = 0;  // act
    ip[16] = 0; ip[17] = 0;                      // hzb
  }
}

// ---------------- gatefin: g[b] = (dot(hm_b, gv[sel])/S + bbs > 0) ----------------
__global__ void gatefin_kernel(const float* __restrict__ hmp, const float* __restrict__ gp,
                               const int* __restrict__ li_p, const float* __restrict__ bbs,
                               int* __restrict__ g) {
  __shared__ float r0[256], r1[256];
  int tid = threadIdx.x;
  const float* partial = gp + (long)(*li_p) * 65536;
  float a0 = 0.f, a1 = 0.f;
  for (int j = tid; j < kH; j += 256) {
    float v = 0.f;
    for (int p = 0; p < 64; ++p) v += partial[(long)p * kH + j];
    float h0 = 0.f, h1 = 0.f;
    #pragma unroll
    for (int z = 0; z < 8; ++z) { h0 += hmp[z * 2048 + j]; h1 += hmp[z * 2048 + kH + j]; }
    a0 += v * h0; a1 += v * h1;
  }
  r0[tid] = a0; r1[tid] = a1;
  __syncthreads();
  for (int st = 128; st; st >>= 1) {
    if (tid < st) { r0[tid] += r0[tid + st]; r1[tid] += r1[tid + st]; }
    __syncthreads();
  }
  if (tid == 0) {
    g[0] = ((r0[0] * (1.f / kS) + bbs[0]) > 0.f) ? 1 : 0;
    g[1] = ((r1[0] * (1.f / kS) + bbs[0]) > 0.f) ? 1 : 0;
  }
}

// ---------------- bf16 MFMA GEMM with f32-B convert-on-stage ----------------
// C = A @ B.T. A: bf16 (M,K). B: f32 weights, converted to bf16 during LDS staging.
// MODE 0: QKV (segmented B = Wq|Wk|Wv rows, bf16 out)
// MODE 1: O    (single B, bf16 out)
// MODE 2: GU   (dual B = Wg,Wu; bf16 out = prod)
// MODE 3: down (single B; f32 C0 + bf16 C1; act-zfill; hzb maintenance)
// MODE 4: final(single B, no li; f32 out; hz fast path)
// BM=128, BN=64, BK=64, 4 waves. A via global_load_lds (pre-swizzled source chunk);
// B via reg-stage cvt + swizzled ds_write; both land in the same XOR layout.
template <int MODE>
__global__ __launch_bounds__(256) void gemm_bf_kernel(
    const u16* __restrict__ A, const float* __restrict__ Bf0, const float* __restrict__ Bf1,
    const float* __restrict__ Bf2, void* __restrict__ C0, void* __restrict__ C1,
    int N, int K, const int* __restrict__ li_p,
    const int* __restrict__ gate, const int* __restrict__ act,
    int* __restrict__ hzwr, const int* __restrict__ hz) {
  constexpr bool USE_B1 = (MODE == 2);
  __shared__ u16 As[128 * 64];
  __shared__ u16 Bs[64 * 64];
  __shared__ u16 Bs1[USE_B1 ? 64 * 64 : 8];

  const int m0 = blockIdx.y * 128, n0 = blockIdx.x * 64;
  const int tid = threadIdx.x;
  const int bb = m0 >> 10;  // 128 | 1024: batch-pure blocks

  if (MODE == 4 && hz != nullptr && hz[bb]) {  // h rows exactly 0 -> out rows 0
    int r = tid >> 1, cb = n0 + (tid & 1) * 32;
    float* c0 = (float*)C0 + (long)(m0 + r) * N + cb;
    float4 z4 = make_float4(0.f, 0.f, 0.f, 0.f);
    #pragma unroll
    for (int j = 0; j < 32; j += 4) *(float4*)(c0 + j) = z4;
    return;
  }
  if (gate != nullptr) {
    int g = gate[bb];
    int ac = (act != nullptr) ? act[bb] : 1;
    if (MODE == 3 && hzwr != nullptr && tid == 0 && blockIdx.x == 0 && (m0 & 1023) == 0) {
      if (g && ac) hzwr[bb] = 0;
      else if (g && !ac) hzwr[bb] = 1;
    }
    if (!g) return;
    if (!ac) {
      if constexpr (MODE == 3) {  // new_h == 0 exactly
        int r = tid >> 1, cb = n0 + (tid & 1) * 32;
        float* c0 = (float*)C0 + (long)(m0 + r) * N + cb;
        u16* c1 = (u16*)C1 + (long)(m0 + r) * N + cb;
        float4 z4 = make_float4(0.f, 0.f, 0.f, 0.f);
        ushort4 zu = {0, 0, 0, 0};
        #pragma unroll
        for (int j = 0; j < 32; j += 4) { *(float4*)(c0 + j) = z4; *(ushort4*)(c1 + j) = zu; }
      }
      return;
    }
  }

  // resolve B row-base pointers (f32)
  long li = (MODE == 4) ? 0 : (long)(*li_p);
  const float* bsrc;
  const float* bsrc1 = nullptr;
  if constexpr (MODE == 0) {
    if (n0 < 1024)      bsrc = Bf0 + li * 1048576 + (long)n0 * kH;
    else if (n0 < 1280) bsrc = Bf1 + li * 262144 + (long)(n0 - 1024) * kH;
    else                bsrc = Bf2 + li * 262144 + (long)(n0 - 1280) * kH;
  } else if constexpr (MODE == 1) {
    bsrc = Bf0 + li * 1048576 + (long)n0 * kH;
  } else if constexpr (MODE == 2) {
    bsrc = Bf0 + li * 4194304 + (long)n0 * kH;
    bsrc1 = Bf1 + li * 4194304 + (long)n0 * kH;
  } else if constexpr (MODE == 3) {
    bsrc = Bf0 + li * 4194304 + (long)n0 * kI;
  } else {
    bsrc = Bf0 + (long)n0 * kH;
  }

  const int wave = tid >> 6, lane = tid & 63;
  const int lr = lane & 15, lg = lane >> 4;
  const int wm = wave >> 1, wn = wave & 1;

  f32x4 acc[4][2] = {};
  f32x4 acc1[USE_B1 ? 4 : 1][2] = {};

  const int sr = tid >> 3, sc8 = tid & 7;           // B-stage row/chunk (j=0)
  const int sr1 = (tid + 256) >> 3;                 // j=1

  for (int k0 = 0; k0 < K; k0 += 64) {
    #pragma unroll
    for (int j = 0; j < 4; ++j) {
      int c = tid + j * 256;
      int r = c >> 3, c8 = c & 7;
      gload16((char*)As + (wave * 64 + j * 256) * 16,
              A + (long)(m0 + r) * K + k0 + ((c8 ^ (r & 7)) * 8));
    }
    #pragma unroll
    for (int j = 0; j < 2; ++j) {
      int r = j ? sr1 : sr, c8 = sc8;
      const float* p = bsrc + (long)r * K + k0 + c8 * 8;
      float4 v0 = *(const float4*)p;
      float4 v1 = *(const float4*)(p + 4);
      short8v o;
      o[0] = (short)f2bf(v0.x); o[1] = (short)f2bf(v0.y);
      o[2] = (short)f2bf(v0.z); o[3] = (short)f2bf(v0.w);
      o[4] = (short)f2bf(v1.x); o[5] = (short)f2bf(v1.y);
      o[6] = (short)f2bf(v1.z); o[7] = (short)f2bf(v1.w);
      *(short8v*)((char*)Bs + ((r * 128 + c8 * 16) ^ ((r & 7) << 4))) = o;
      if constexpr (USE_B1) {
        const float* p1 = bsrc1 + (long)r * K + k0 + c8 * 8;
        float4 w0 = *(const float4*)p1;
        float4 w1 = *(const float4*)(p1 + 4);
        short8v o1;
        o1[0] = (short)f2bf(w0.x); o1[1] = (short)f2bf(w0.y);
        o1[2] = (short)f2bf(w0.z); o1[3] = (short)f2bf(w0.w);
        o1[4] = (short)f2bf(w1.x); o1[5] = (short)f2bf(w1.y);
        o1[6] = (short)f2bf(w1.z); o1[7] = (short)f2bf(w1.w);
        *(short8v*)((char*)Bs1 + ((r * 128 + c8 * 16) ^ ((r & 7) << 4))) = o1;
      }
    }
    __syncthreads();
    #pragma unroll
    for (int kh = 0; kh < 2; ++kh) {
      const int kb = kh * 64 + lg * 16;
      short8v av[4], bv[2], b1v[2];
      #pragma unroll
      for (int mi = 0; mi < 4; ++mi) {
        int r = wm * 64 + mi * 16 + lr;
        av[mi] = *(const short8v*)((const char*)As + ((r * 128 + kb) ^ ((r & 7) << 4)));
      }
      #pragma unroll
      for (int ni = 0; ni < 2; ++ni) {
        int r = wn * 32 + ni * 16 + lr;
        int byte = (r * 128 + kb) ^ ((r & 7) << 4);
        bv[ni] = *(const short8v*)((const char*)Bs + byte);
        if constexpr (USE_B1) b1v[ni] = *(const short8v*)((const char*)Bs1 + byte);
      }
      #pragma unroll
      for (int mi = 0; mi < 4; ++mi)
        #pragma unroll
        for (int ni = 0; ni < 2; ++ni) {
          acc[mi][ni] = MFMA16(av[mi], bv[ni], acc[mi][ni], 0, 0, 0);
          if constexpr (USE_B1)
            acc1[mi][ni] = MFMA16(av[mi], b1v[ni], acc1[mi][ni], 0, 0, 0);
        }
    }
    __syncthreads();
  }
  #pragma unroll
  for (int mi = 0; mi < 4; ++mi)
    #pragma unroll
    for (int ni = 0; ni < 2; ++ni)
      #pragma unroll
      for (int r = 0; r < 4; ++r) {
        long idx = (long)(m0 + wm * 64 + mi * 16 + lg * 4 + r) * N +
                   (n0 + wn * 32 + ni * 16 + lr);
        float v = acc[mi][ni][r];
        if constexpr (MODE == 0 || MODE == 1) ((u16*)C0)[idx] = f2bf(v);
        if constexpr (MODE == 2) ((u16*)C0)[idx] = f2bf(v * acc1[mi][ni][r]);
        if constexpr (MODE == 3) { ((float*)C0)[idx] = v; ((u16*)C1)[idx] = f2bf(v); }
        if constexpr (MODE == 4) ((float*)C0)[idx] = v;
      }
}

// ---------------- rowsum(thresholded softmax) + fused attn = rs*V ----------------
// grid (64, 4, 2): 16 q-rows x 4 heads of one kv-group; 4 waves split the k-range.
// Online max; pass 2 skipped block-uniformly when no element can pass (S >= 100).
__global__ __launch_bounds__(256) void rowsum_kernel(
    const u16* __restrict__ QKV, const int* __restrict__ gate, int* __restrict__ act,
    u16* __restrict__ ATT) {
  int b = blockIdx.z;
  if (!gate[b]) return;
  int kvg = blockIdx.y, qt = blockIdx.x;
  int tid = threadIdx.x;
  int w = tid >> 6, lane = tid & 63, lr = lane & 15, lg = lane >> 4;

  __shared__ float sm[4][64], ss[4][64], st[4][64], srs[64];
  __shared__ int sskip;
  if (tid == 0) sskip = 0;

  long qrow = ((long)b << 10) + qt * 16 + lr;
  short8v qlo[4], qhi[4];
  #pragma unroll
  for (int hh = 0; hh < 4; ++hh) {
    const u16* qp = QKV + qrow * kQKVN + (kvg * 4 + hh) * 64 + lg * 8;
    qlo[hh] = *(const short8v*)qp;
    qhi[hh] = *(const short8v*)(qp + 32);
  }
  const u16* kb0 = QKV + (((long)b << 10) + w * 256 + lr) * kQKVN + 1024 + kvg * 64 + lg * 8;

  float m[4][4], s[4][4];
  #pragma unroll
  for (int hh = 0; hh < 4; ++hh)
    #pragma unroll
    for (int i = 0; i < 4; ++i) { m[hh][i] = -3e38f; s[hh][i] = 0.f; }
  for (int kt = 0; kt < 16; ++kt) {
    const u16* kp = kb0 + (long)kt * 16 * kQKVN;
    short8v klo = *(const short8v*)kp;
    short8v khi = *(const short8v*)(kp + 32);
    #pragma unroll
    for (int hh = 0; hh < 4; ++hh) {
      f32x4 c = {0.f, 0.f, 0.f, 0.f};
      c = MFMA16(qlo[hh], klo, c, 0, 0, 0);
      c = MFMA16(qhi[hh], khi, c, 0, 0, 0);
      #pragma unroll
      for (int i = 0; i < 4; ++i) {
        float x = c[i] * 0.125f;
        if (x > m[hh][i]) { s[hh][i] = s[hh][i] * __expf(m[hh][i] - x) + 1.f; m[hh][i] = x; }
        else s[hh][i] += __expf(x - m[hh][i]);
      }
    }
  }
  #pragma unroll
  for (int off = 1; off < 16; off <<= 1)
    #pragma unroll
    for (int hh = 0; hh < 4; ++hh)
      #pragma unroll
      for (int i = 0; i < 4; ++i) {
        float mo = __shfl_xor(m[hh][i], off);
        float so = __shfl_xor(s[hh][i], off);
        float mn = fmaxf(m[hh][i], mo);
        s[hh][i] = s[hh][i] * __expf(m[hh][i] - mn) + so * __expf(mo - mn);
        m[hh][i] = mn;
      }
  if (lr == 0)
    #pragma unroll
    for (int hh = 0; hh < 4; ++hh)
      #pragma unroll
      for (int i = 0; i < 4; ++i) {
        sm[w][hh * 16 + lg * 4 + i] = m[hh][i];
        ss[w][hh * 16 + lg * 4 + i] = s[hh][i];
      }
  __syncthreads();
  float Mg[4][4], Sg[4][4];
  int need = 0;
  #pragma unroll
  for (int hh = 0; hh < 4; ++hh)
    #pragma unroll
    for (int i = 0; i < 4; ++i) {
      int q = hh * 16 + lg * 4 + i;
      float mm = fmaxf(fmaxf(sm[0][q], sm[1][q]), fmaxf(sm[2][q], sm[3][q]));
      float SS = ss[0][q] * __expf(sm[0][q] - mm) + ss[1][q] * __expf(sm[1][q] - mm) +
                 ss[2][q] * __expf(sm[2][q] - mm) + ss[3][q] * __expf(sm[3][q] - mm);
      Mg[hh][i] = mm; Sg[hh][i] = SS;
      need |= (SS < 100.f) ? 1 : 0;
    }
  if (need) atomicOr(&sskip, 1);
  __syncthreads();
  int do2 = sskip;
  if (do2) {
    float tt[4][4] = {};
    for (int kt = 0; kt < 16; ++kt) {
      const u16* kp = kb0 + (long)kt * 16 * kQKVN;
      short8v klo = *(const short8v*)kp;
      short8v khi = *(const short8v*)(kp + 32);
      #pragma unroll
      for (int hh = 0; hh < 4; ++hh) {
        f32x4 c = {0.f, 0.f, 0.f, 0.f};
        c = MFMA16(qlo[hh], klo, c, 0, 0, 0);
        c = MFMA16(qhi[hh], khi, c, 0, 0, 0);
        #pragma unroll
        for (int i = 0; i < 4; ++i) {
          float e = __expf(c[i] * 0.125f - Mg[hh][i]);
          if (e > 0.01f * Sg[hh][i]) tt[hh][i] += e;
        }
      }
    }
    #pragma unroll
    for (int off = 1; off < 16; off <<= 1)
      #pragma unroll
      for (int hh = 0; hh < 4; ++hh)
        #pragma unroll
        for (int i = 0; i < 4; ++i) tt[hh][i] += __shfl_xor(tt[hh][i], off);
    if (lr == 0)
      #pragma unroll
      for (int hh = 0; hh < 4; ++hh)
        #pragma unroll
        for (int i = 0; i < 4; ++i) st[w][hh * 16 + lg * 4 + i] = tt[hh][i];
  }
  __syncthreads();
  if (tid < 64) {
    int hh = tid >> 4, q = tid & 15;
    float T = do2 ? (st[0][hh * 16 + q] + st[1][hh * 16 + q] + st[2][hh * 16 + q] +
                     st[3][hh * 16 + q])
                  : 0.f;
    float mm = fmaxf(fmaxf(sm[0][hh * 16 + q], sm[1][hh * 16 + q]),
                     fmaxf(sm[2][hh * 16 + q], sm[3][hh * 16 + q]));
    float SS = ss[0][hh * 16 + q] * __expf(sm[0][hh * 16 + q] - mm) +
               ss[1][hh * 16 + q] * __expf(sm[1][hh * 16 + q] - mm) +
               ss[2][hh * 16 + q] * __expf(sm[2][hh * 16 + q] - mm) +
               ss[3][hh * 16 + q] * __expf(sm[3][hh * 16 + q] - mm);
    srs[hh * 16 + q] = T / SS;
    if (T > 0.f) atomicOr(act + b, 1);
  }
  __syncthreads();
  int hh = tid >> 6, rr = (tid >> 2) & 15, d0 = (tid & 3) * 16;
  float rv = srs[hh * 16 + rr];
  long row = ((long)b << 10) + qt * 16 + rr;
  const u16* vp = QKV + row * kQKVN + 1280 + kvg * 64 + d0;
  u16* op = ATT + row * kH + (kvg * 4 + hh) * 64 + d0;
  #pragma unroll
  for (int j = 0; j < 16; j += 4) {
    ushort4 v = *(const ushort4*)(vp + j);
    ushort4 o;
    o.x = f2bf(rv * bf2f(v.x)); o.y = f2bf(rv * bf2f(v.y));
    o.z = f2bf(rv * bf2f(v.z)); o.w = f2bf(rv * bf2f(v.w));
    *(ushort4*)(op + j) = o;
  }
}

// ---------------- launch ----------------
extern "C" void kernel_launch(void* const* d_in, const int* in_sizes, int n_in,
                              void* d_out, int out_size, void* d_ws, size_t ws_size,
                              hipStream_t stream) {
  (void)in_sizes; (void)n_in; (void)out_size; (void)ws_size;
  const int*   ids  = (const int*)d_in[0];
  const float* emb  = (const float*)d_in[1];
  const float* semb = (const float*)d_in[2];
  const float* Wq   = (const float*)d_in[3];
  const float* Wk   = (const float*)d_in[4];
  const float* Wv   = (const float*)d_in[5];
  const float* Wo   = (const float*)d_in[6];
  const float* Wg   = (const float*)d_in[7];
  const float* Wu   = (const float*)d_in[8];
  const float* Wd   = (const float*)d_in[9];
  const float* Wls  = (const float*)d_in[10];
  const float* bls  = (const float*)d_in[11];
  const float* Wbs  = (const float*)d_in[12];
  const float* bbs  = (const float*)d_in[13];
  const float* Wout = (const float*)d_in[14];
  float* out = (float*)d_out;
  float* ws  = (float*)d_ws;

  float* h   = ws + OFF_H;
  float* hmp = ws + OFF_HMP;
  int* ip    = (int*)(ws + OFF_INT);
  int* sel   = ip + 1;
  int* gate  = ip + 4;
  int* act   = ip + 10;
  int* hzb   = ip + 16;
  float* gp  = ws + OFF_GP;
  u16* hbf   = (u16*)(ws + OFF_HBF);
  u16* QKV   = (u16*)(ws + OFF_QKV);
  u16* ATT   = (u16*)(ws + OFF_ATT);
  u16* Obf   = (u16*)(ws + OFF_OBF);
  u16* Pbf   = (u16*)(ws + OFF_PBF);

  embed_gv_kernel<<<2240, 256, 0, stream>>>(ids, emb, semb, Wq, Wbs, h, hbf, gp);
  hmean_kernel<<<dim3(4, 2, 8), 256, 0, stream>>>(h, hmp);
  scores_kernel<<<1, 256, 0, stream>>>(hmp, Wls, bls, ip);

  for (int i = 0; i < 3; i++) {
    const int* li = sel + i;
    int* g_i = gate + 2 * i;
    int* a_i = act + 2 * i;

    if (i > 0) hmean_kernel<<<dim3(4, 2, 8), 256, 0, stream>>>(h, hmp);
    gatefin_kernel<<<1, 256, 0, stream>>>(hmp, gp, li, bbs, g_i);
    // QKV = h @ [Wq|Wk|Wv].T  (B converted on stage)
    gemm_bf_kernel<0><<<dim3(kQKVN / 64, 16), 256, 0, stream>>>(
        hbf, Wq, Wk, Wv, QKV, nullptr, kQKVN, kH, li, g_i, nullptr, nullptr, nullptr);
    // thresholded-softmax rowsum + attn (sets act)
    rowsum_kernel<<<dim3(64, 4, 2), 256, 0, stream>>>(QKV, g_i, a_i, ATT);
    // O = attn @ wo.T
    gemm_bf_kernel<1><<<dim3(kH / 64, 16), 256, 0, stream>>>(
        ATT, Wo, nullptr, nullptr, Obf, nullptr, kH, kH, li, g_i, a_i, nullptr, nullptr);
    // P = (O @ wg.T) * (O @ wu.T)
    gemm_bf_kernel<2><<<dim3(kI / 64, 16), 256, 0, stream>>>(
        Obf, Wg, Wu, nullptr, Pbf, nullptr, kI, kH, li, g_i, a_i, nullptr, nullptr);
    // h = P @ wd.T -> f32 h + bf16 hbf; act-zfill + hzb maintenance
    gemm_bf_kernel<3><<<dim3(kH / 64, 16), 256, 0, stream>>>(
        Pbf, Wd, nullptr, nullptr, h, hbf, kH, kI, li, g_i, a_i, hzb, nullptr);
  }
  // out = h @ Wout[:2560].T (per-batch zero fast path when h==0)
  gemm_bf_kernel<4><<<dim3(kNOUT / 64, 16), 256, 0, stream>>>(
      hbf, Wout, nullptr, nullptr, out, nullptr, kNOUT, kH, nullptr, nullptr, nullptr,
      nullptr, hzb);
}